// Round 1
// baseline (2123.016 us; speedup 1.0000x reference)
//
#include <hip/hip_runtime.h>

#define NN 100000
#define NE 1600000
#define EPS_BN 1e-5f

__device__ __forceinline__ float lk(float x){ return x >= 0.f ? x : 0.1f*x; }

// ---------------- degree / dinv ----------------
__global__ void init_nodes(float* __restrict__ deg, int* __restrict__ cnt, int n){
  int i = blockIdx.x*256 + threadIdx.x;
  if (i < n){ deg[i] = 1.0f; cnt[i] = 0; }
}

__global__ void edge_deg(const int* __restrict__ dst, const float* __restrict__ ew,
                         float* __restrict__ deg, int* __restrict__ cnt, int e){
  int i = blockIdx.x*256 + threadIdx.x;
  if (i < e){
    int d = dst[i];
    atomicAdd(&deg[d], ew[i]);
    atomicAdd(&cnt[d], 1);
  }
}

__global__ void finalize_dinv(float* __restrict__ deg, int n){
  int i = blockIdx.x*256 + threadIdx.x;
  if (i < n) deg[i] = rsqrtf(deg[i]);   // deg >= 1 always (self loop)
}

// ---------------- exclusive scan (3-kernel) ----------------
__global__ __launch_bounds__(1024) void scan_block(const int* __restrict__ in, int* __restrict__ out,
                                                   int* __restrict__ bsum, int n){
  __shared__ int s[1024];
  int t = threadIdx.x;
  int i = blockIdx.x*1024 + t;
  int v = (i < n) ? in[i] : 0;
  s[t] = v; __syncthreads();
  for (int off = 1; off < 1024; off <<= 1){
    int x = (t >= off) ? s[t-off] : 0;
    __syncthreads();
    s[t] += x;
    __syncthreads();
  }
  if (i < n) out[i] = s[t] - v;          // exclusive within chunk
  if (t == 1023) bsum[blockIdx.x] = s[1023];
}

__global__ void scan_small(int* __restrict__ bsum, int nb){
  __shared__ int s[128];
  int t = threadIdx.x;
  int v = (t < nb) ? bsum[t] : 0;
  s[t] = v; __syncthreads();
  for (int off = 1; off < 128; off <<= 1){
    int x = (t >= off) ? s[t-off] : 0;
    __syncthreads();
    s[t] += x;
    __syncthreads();
  }
  if (t < nb) bsum[t] = s[t] - v;        // exclusive
}

__global__ __launch_bounds__(1024) void scan_add(int* __restrict__ rp, int* __restrict__ fill,
                                                 const int* __restrict__ bsum, int n, int etot){
  int i = blockIdx.x*1024 + threadIdx.x;
  if (i < n){
    int v = rp[i] + bsum[blockIdx.x];
    rp[i] = v;
    fill[i] = v;
  }
  if (i == 0) rp[n] = etot;
}

// ---------------- CSR fill ----------------
__global__ void fill_csr_k(const int* __restrict__ src, const int* __restrict__ dst,
                           const float* __restrict__ ew, const float* __restrict__ dinv,
                           int* __restrict__ fill, int* __restrict__ csr_src,
                           float* __restrict__ csr_w, int e){
  int i = blockIdx.x*256 + threadIdx.x;
  if (i >= e) return;
  int s = src[i], d = dst[i];
  int pos = atomicAdd(&fill[d], 1);
  csr_src[pos] = s;
  csr_w[pos] = dinv[s] * ew[i] * dinv[d];
}

// ---------------- SpMM (gather by destination, no atomics) ----------------
// out[node, :] = dinv[node]^2 * h[node, :] + bias + sum_e csr_w[e] * h[csr_src[e], :]
__global__ __launch_bounds__(256) void spmm_kern(const float* __restrict__ h,
    const int* __restrict__ rp, const int* __restrict__ csr_src, const float* __restrict__ csr_w,
    const float* __restrict__ dinv, const float* __restrict__ bias,
    float* __restrict__ out, int n){
  int node = blockIdx.x*4 + (threadIdx.x >> 6);   // one wave64 per node, 4 floats/lane = 256 ch
  if (node >= n) return;
  int lane = threadIdx.x & 63;
  float di = dinv[node];
  float c0 = di * di;
  float4 hv = *(const float4*)(h + (size_t)node*256 + lane*4);
  float4 bb = *(const float4*)(bias + lane*4);
  float4 acc;
  acc.x = fmaf(c0, hv.x, bb.x);
  acc.y = fmaf(c0, hv.y, bb.y);
  acc.z = fmaf(c0, hv.z, bb.z);
  acc.w = fmaf(c0, hv.w, bb.w);
  int p = rp[node], pend = rp[node+1];
  for (; p < pend; ++p){
    int s = csr_src[p];
    float w = csr_w[p];
    float4 v = *(const float4*)(h + (size_t)s*256 + lane*4);
    acc.x = fmaf(w, v.x, acc.x);
    acc.y = fmaf(w, v.y, acc.y);
    acc.z = fmaf(w, v.z, acc.z);
    acc.w = fmaf(w, v.w, acc.w);
  }
  *(float4*)(out + (size_t)node*256 + lane*4) = acc;
}

// ---------------- BatchNorm ----------------
__global__ void zero_stats(float* __restrict__ stats){
  stats[threadIdx.x] = 0.f;   // 512 threads
}

__global__ __launch_bounds__(256) void bn_partial(const float* __restrict__ a,
                                                  float* __restrict__ stats, int n){
  int c = threadIdx.x;                 // channel 0..255
  int r0 = blockIdx.x * 256;
  int rend = min(r0 + 256, n);
  float s = 0.f, s2 = 0.f;
  for (int r = r0; r < rend; ++r){
    float v = a[(size_t)r*256 + c];
    s += v;
    s2 = fmaf(v, v, s2);
  }
  atomicAdd(&stats[c], s);
  atomicAdd(&stats[256 + c], s2);
}

__global__ void bn_final(float* __restrict__ stats, const float* __restrict__ g,
                         const float* __restrict__ be, int n){
  int c = threadIdx.x;                 // 256 threads
  float inv_n = 1.0f / (float)n;
  float mean = stats[c] * inv_n;
  float var  = fmaxf(stats[256 + c] * inv_n - mean*mean, 0.f);
  float sc   = g[c] * rsqrtf(var + EPS_BN);
  stats[512 + c] = sc;
  stats[768 + c] = be[c] - mean * sc;
}

__global__ __launch_bounds__(256) void bn_apply(float* __restrict__ a,
                                                const float* __restrict__ stats, int n){
  size_t i = (size_t)blockIdx.x*256 + threadIdx.x;   // one float4 per thread
  if (i >= (size_t)n*64) return;
  int c4 = (int)(i & 63);
  float4 v  = ((float4*)a)[i];
  float4 sc = ((const float4*)(stats + 512))[c4];
  float4 sh = ((const float4*)(stats + 768))[c4];
  v.x = lk(fmaf(v.x, sc.x, sh.x));
  v.y = lk(fmaf(v.y, sc.y, sh.y));
  v.z = lk(fmaf(v.z, sc.z, sh.z));
  v.w = lk(fmaf(v.w, sc.w, sh.w));
  ((float4*)a)[i] = v;
}

// ---------------- fp32 tiled GEMM ----------------
// C[n,M] = A[n,K] @ B[K,M]  (+ bias, + leaky per ACT)
// ACT: 0 = none, 1 = bias+leaky, 2 = bias
template<int BM, int BN, int BK, int TM, int TN, int ACT>
__global__ __launch_bounds__(256) void gemm_kern(const float* __restrict__ A,
                                                 const float* __restrict__ B,
                                                 const float* __restrict__ bias,
                                                 float* __restrict__ C,
                                                 int nrows, int K, int M){
  static_assert((BM/TM)*(BN/TN) == 256, "256 threads");
  __shared__ float As[BK][BM];
  __shared__ float Bs[BK][BN];
  const int tid = threadIdx.x;
  const int r0 = blockIdx.x * BM;
  const int c0 = blockIdx.y * BN;
  constexpr int TCOLS = BN / TN;
  const int tr = tid / TCOLS;
  const int tc = tid % TCOLS;
  float acc[TM][TN];
#pragma unroll
  for (int i = 0; i < TM; ++i)
#pragma unroll
    for (int j = 0; j < TN; ++j) acc[i][j] = 0.f;

  constexpr int A_F4 = BM*BK/4;
  constexpr int B_F4 = BK*BN/4;

  for (int kt = 0; kt < K; kt += BK){
    for (int i = tid; i < A_F4; i += 256){
      int row = i / (BK/4);
      int kq  = i % (BK/4);
      float4 v = make_float4(0.f, 0.f, 0.f, 0.f);
      int gr = r0 + row;
      if (gr < nrows) v = *(const float4*)(A + (size_t)gr*K + kt + kq*4);
      As[kq*4+0][row] = v.x;
      As[kq*4+1][row] = v.y;
      As[kq*4+2][row] = v.z;
      As[kq*4+3][row] = v.w;
    }
    for (int i = tid; i < B_F4; i += 256){
      int krow = i / (BN/4);
      int cq   = i % (BN/4);
      *(float4*)&Bs[krow][cq*4] = *(const float4*)(B + (size_t)(kt+krow)*M + c0 + cq*4);
    }
    __syncthreads();
#pragma unroll
    for (int kk = 0; kk < BK; ++kk){
      float a[TM], b[TN];
#pragma unroll
      for (int i = 0; i < TM; ++i) a[i] = As[kk][tr*TM + i];
#pragma unroll
      for (int j = 0; j < TN; ++j) b[j] = Bs[kk][tc*TN + j];
#pragma unroll
      for (int i = 0; i < TM; ++i)
#pragma unroll
        for (int j = 0; j < TN; ++j)
          acc[i][j] = fmaf(a[i], b[j], acc[i][j]);
    }
    __syncthreads();
  }

#pragma unroll
  for (int i = 0; i < TM; ++i){
    int gr = r0 + tr*TM + i;
    if (gr >= nrows) continue;
#pragma unroll
    for (int j = 0; j < TN; j += 4){
      int gc = c0 + tc*TN + j;
      float4 v = make_float4(acc[i][j], acc[i][j+1], acc[i][j+2], acc[i][j+3]);
      if (ACT >= 1){
        float4 bb = *(const float4*)(bias + gc);
        v.x += bb.x; v.y += bb.y; v.z += bb.z; v.w += bb.w;
      }
      if (ACT == 1){
        v.x = lk(v.x); v.y = lk(v.y); v.z = lk(v.z); v.w = lk(v.w);
      }
      *(float4*)(C + (size_t)gr*M + gc) = v;
    }
  }
}

// ---------------- launch ----------------
extern "C" void kernel_launch(void* const* d_in, const int* in_sizes, int n_in,
                              void* d_out, int out_size, void* d_ws, size_t ws_size,
                              hipStream_t stream){
  const float* x   = (const float*)d_in[0];
  const int*   ei  = (const int*)  d_in[1];
  const float* ew  = (const float*)d_in[2];
  const float* W1  = (const float*)d_in[3];
  const float* b1  = (const float*)d_in[4];
  const float* g1  = (const float*)d_in[5];
  const float* be1 = (const float*)d_in[6];
  const float* W2  = (const float*)d_in[7];
  const float* b2  = (const float*)d_in[8];
  const float* g2  = (const float*)d_in[9];
  const float* be2 = (const float*)d_in[10];
  const float* W3  = (const float*)d_in[11];
  const float* b3  = (const float*)d_in[12];
  const float* g3  = (const float*)d_in[13];
  const float* be3 = (const float*)d_in[14];
  const float* Wl1 = (const float*)d_in[15];
  const float* bl1 = (const float*)d_in[16];
  const float* Wl2 = (const float*)d_in[17];
  const float* bl2 = (const float*)d_in[18];
  const int* src = ei;
  const int* dst = ei + NE;

  char* p = (char*)d_ws;
  auto carve = [&](size_t bytes)->void*{
    void* r = (void*)p;
    p += (bytes + 255) & ~(size_t)255;
    return r;
  };
  float* dinv    = (float*)carve((size_t)NN*4);
  int*   rp      = (int*)  carve((size_t)(NN+1)*4);
  int*   fill    = (int*)  carve((size_t)NN*4);
  int*   cnt     = (int*)  carve((size_t)NN*4);
  int*   bsum    = (int*)  carve(256*4);
  float* stats   = (float*)carve(1024*4);
  int*   csr_src = (int*)  carve((size_t)NE*4);
  float* csr_w   = (float*)carve((size_t)NE*4);
  float* bufA    = (float*)carve((size_t)NN*256*4);
  float* bufB    = (float*)carve((size_t)NN*256*4);

  const int nb = (NN + 1023) / 1024;   // 98 scan blocks

  // degree + dinv + CSR (shared by all 3 conv layers)
  init_nodes<<<(NN+255)/256, 256, 0, stream>>>(dinv, cnt, NN);
  edge_deg<<<(NE+255)/256, 256, 0, stream>>>(dst, ew, dinv, cnt, NE);
  finalize_dinv<<<(NN+255)/256, 256, 0, stream>>>(dinv, NN);
  scan_block<<<nb, 1024, 0, stream>>>(cnt, rp, bsum, NN);
  scan_small<<<1, 128, 0, stream>>>(bsum, nb);
  scan_add<<<nb, 1024, 0, stream>>>(rp, fill, bsum, NN, NE);
  fill_csr_k<<<(NE+255)/256, 256, 0, stream>>>(src, dst, ew, dinv, fill, csr_src, csr_w, NE);

  dim3 gridBig((NN+127)/128, 2);   // 256 cols / BN=128
  dim3 gridOut((NN+127)/128, 1);   // 32 cols  / BN=32

  auto run_bn = [&](float* buf, const float* g, const float* be){
    zero_stats<<<1, 512, 0, stream>>>(stats);
    bn_partial<<<(NN+255)/256, 256, 0, stream>>>(buf, stats, NN);
    bn_final<<<1, 256, 0, stream>>>(stats, g, be, NN);
    bn_apply<<<(int)(((size_t)NN*64 + 255)/256), 256, 0, stream>>>(buf, stats, NN);
  };

  // conv1: h = x @ W1 ; agg ; bn ; leaky
  gemm_kern<128,128,8,8,8,0><<<gridBig, 256, 0, stream>>>(x, W1, nullptr, bufA, NN, 128, 256);
  spmm_kern<<<(NN+3)/4, 256, 0, stream>>>(bufA, rp, csr_src, csr_w, dinv, b1, bufB, NN);
  run_bn(bufB, g1, be1);

  // conv2
  gemm_kern<128,128,8,8,8,0><<<gridBig, 256, 0, stream>>>(bufB, W2, nullptr, bufA, NN, 256, 256);
  spmm_kern<<<(NN+3)/4, 256, 0, stream>>>(bufA, rp, csr_src, csr_w, dinv, b2, bufB, NN);
  run_bn(bufB, g2, be2);

  // conv3
  gemm_kern<128,128,8,8,8,0><<<gridBig, 256, 0, stream>>>(bufB, W3, nullptr, bufA, NN, 256, 256);
  spmm_kern<<<(NN+3)/4, 256, 0, stream>>>(bufA, rp, csr_src, csr_w, dinv, b3, bufB, NN);
  run_bn(bufB, g3, be3);

  // head: leaky(h @ Wl1 + bl1) @ Wl2 + bl2
  gemm_kern<128,128,8,8,8,1><<<gridBig, 256, 0, stream>>>(bufB, Wl1, bl1, bufA, NN, 256, 256);
  gemm_kern<128,32,8,4,4,2><<<gridOut, 256, 0, stream>>>(bufA, Wl2, bl2, (float*)d_out, NN, 256, 32);
}

// Round 3
// 1722.708 us; speedup vs baseline: 1.2324x; 1.2324x over previous
//
#include <hip/hip_runtime.h>

#define NN 100000
#define NE 1600000
#define EPS_BN 1e-5f

typedef unsigned short ushort_t;
typedef short v8s __attribute__((ext_vector_type(8)));   // 8 bf16 (4 VGPR)
typedef float v4f __attribute__((ext_vector_type(4)));   // 4 fp32 acc

__device__ __forceinline__ float lk(float x){ return x >= 0.f ? x : 0.1f*x; }

__device__ __forceinline__ ushort_t f2bf(float x){
  unsigned u = __float_as_uint(x);
  unsigned r = (u + 0x7fffu + ((u >> 16) & 1u)) >> 16;
  return (ushort_t)r;
}
__device__ __forceinline__ float bf2f(ushort_t h){
  return __uint_as_float(((unsigned)h) << 16);
}
__device__ __forceinline__ void split2(float x, ushort_t& hi, ushort_t& lo){
  hi = f2bf(x);
  lo = f2bf(x - bf2f(hi));
}

// async 16B global->LDS (lds dst is wave-uniform base; HW adds lane*16)
__device__ __forceinline__ void gload16(const ushort_t* g, ushort_t* l){
  __builtin_amdgcn_global_load_lds((const __attribute__((address_space(1))) void*)g,
                                   (__attribute__((address_space(3))) void*)l, 16, 0, 0);
}

// ---------------- degree / dinv ----------------
__global__ void init_nodes(float* __restrict__ deg, int* __restrict__ cnt, int n){
  int i = blockIdx.x*256 + threadIdx.x;
  if (i < n){ deg[i] = 1.0f; cnt[i] = 0; }
}

__global__ void edge_deg(const int* __restrict__ dst, const float* __restrict__ ew,
                         float* __restrict__ deg, int* __restrict__ cnt, int e){
  int i = blockIdx.x*256 + threadIdx.x;
  if (i < e){
    int d = dst[i];
    atomicAdd(&deg[d], ew[i]);
    atomicAdd(&cnt[d], 1);
  }
}

__global__ void finalize_dinv(float* __restrict__ deg, int n){
  int i = blockIdx.x*256 + threadIdx.x;
  if (i < n) deg[i] = rsqrtf(deg[i]);
}

// ---------------- exclusive scan (3-kernel) ----------------
__global__ __launch_bounds__(1024) void scan_block(const int* __restrict__ in, int* __restrict__ out,
                                                   int* __restrict__ bsum, int n){
  __shared__ int s[1024];
  int t = threadIdx.x;
  int i = blockIdx.x*1024 + t;
  int v = (i < n) ? in[i] : 0;
  s[t] = v; __syncthreads();
  for (int off = 1; off < 1024; off <<= 1){
    int x = (t >= off) ? s[t-off] : 0;
    __syncthreads();
    s[t] += x;
    __syncthreads();
  }
  if (i < n) out[i] = s[t] - v;
  if (t == 1023) bsum[blockIdx.x] = s[1023];
}

__global__ void scan_small(int* __restrict__ bsum, int nb){
  __shared__ int s[128];
  int t = threadIdx.x;
  int v = (t < nb) ? bsum[t] : 0;
  s[t] = v; __syncthreads();
  for (int off = 1; off < 128; off <<= 1){
    int x = (t >= off) ? s[t-off] : 0;
    __syncthreads();
    s[t] += x;
    __syncthreads();
  }
  if (t < nb) bsum[t] = s[t] - v;
}

__global__ __launch_bounds__(1024) void scan_add(int* __restrict__ rp, int* __restrict__ fill,
                                                 const int* __restrict__ bsum, int n, int etot){
  int i = blockIdx.x*1024 + threadIdx.x;
  if (i < n){
    int v = rp[i] + bsum[blockIdx.x];
    rp[i] = v;
    fill[i] = v;
  }
  if (i == 0) rp[n] = etot;
}

// ---------------- CSR fill ----------------
__global__ void fill_csr_k(const int* __restrict__ src, const int* __restrict__ dst,
                           const float* __restrict__ ew, const float* __restrict__ dinv,
                           int* __restrict__ fill, int* __restrict__ csr_src,
                           float* __restrict__ csr_w, int e){
  int i = blockIdx.x*256 + threadIdx.x;
  if (i >= e) return;
  int s = src[i], d = dst[i];
  int pos = atomicAdd(&fill[d], 1);
  csr_src[pos] = s;
  csr_w[pos] = dinv[s] * ew[i] * dinv[d];
}

// ---------------- SpMM (gather by destination, no atomics) ----------------
__global__ __launch_bounds__(256) void spmm_kern(const float* __restrict__ h,
    const int* __restrict__ rp, const int* __restrict__ csr_src, const float* __restrict__ csr_w,
    const float* __restrict__ dinv, const float* __restrict__ bias,
    float* __restrict__ out, int n){
  int node = blockIdx.x*4 + (threadIdx.x >> 6);
  if (node >= n) return;
  int lane = threadIdx.x & 63;
  float di = dinv[node];
  float c0 = di * di;
  float4 hv = *(const float4*)(h + (size_t)node*256 + lane*4);
  float4 bb = *(const float4*)(bias + lane*4);
  float4 acc;
  acc.x = fmaf(c0, hv.x, bb.x);
  acc.y = fmaf(c0, hv.y, bb.y);
  acc.z = fmaf(c0, hv.z, bb.z);
  acc.w = fmaf(c0, hv.w, bb.w);
  int p = rp[node], pend = rp[node+1];
  for (; p < pend; ++p){
    int s = csr_src[p];
    float w = csr_w[p];
    float4 v = *(const float4*)(h + (size_t)s*256 + lane*4);
    acc.x = fmaf(w, v.x, acc.x);
    acc.y = fmaf(w, v.y, acc.y);
    acc.z = fmaf(w, v.z, acc.z);
    acc.w = fmaf(w, v.w, acc.w);
  }
  *(float4*)(out + (size_t)node*256 + lane*4) = acc;
}

// ---------------- BatchNorm ----------------
__global__ void zero_stats(float* __restrict__ stats){
  stats[threadIdx.x] = 0.f;   // 512 threads
}

__global__ __launch_bounds__(256) void bn_partial(const float* __restrict__ a,
                                                  float* __restrict__ stats, int n){
  int c = threadIdx.x;
  int r0 = blockIdx.x * 256;
  int rend = min(r0 + 256, n);
  float s = 0.f, s2 = 0.f;
  for (int r = r0; r < rend; ++r){
    float v = a[(size_t)r*256 + c];
    s += v;
    s2 = fmaf(v, v, s2);
  }
  atomicAdd(&stats[c], s);
  atomicAdd(&stats[256 + c], s2);
}

__global__ void bn_final(float* __restrict__ stats, const float* __restrict__ g,
                         const float* __restrict__ be, int n){
  int c = threadIdx.x;
  float inv_n = 1.0f / (float)n;
  float mean = stats[c] * inv_n;
  float var  = fmaxf(stats[256 + c] * inv_n - mean*mean, 0.f);
  float sc   = g[c] * rsqrtf(var + EPS_BN);
  stats[512 + c] = sc;
  stats[768 + c] = be[c] - mean * sc;
}

// bn scale/shift + leaky, emit hi/lo bf16 split directly (feeds next MFMA GEMM)
__global__ __launch_bounds__(256) void bn_apply_split(const float* __restrict__ a,
    const float* __restrict__ stats, ushort_t* __restrict__ hi, ushort_t* __restrict__ lo, int n){
  size_t i = (size_t)blockIdx.x*256 + threadIdx.x;   // one float4 per thread
  if (i >= (size_t)n*64) return;
  int c4 = (int)(i & 63);
  float4 v  = ((const float4*)a)[i];
  float4 sc = ((const float4*)(stats + 512))[c4];
  float4 sh = ((const float4*)(stats + 768))[c4];
  v.x = lk(fmaf(v.x, sc.x, sh.x));
  v.y = lk(fmaf(v.y, sc.y, sh.y));
  v.z = lk(fmaf(v.z, sc.z, sh.z));
  v.w = lk(fmaf(v.w, sc.w, sh.w));
  ushort4 h, l;
  split2(v.x, h.x, l.x); split2(v.y, h.y, l.y);
  split2(v.z, h.z, l.z); split2(v.w, h.w, l.w);
  ((ushort4*)hi)[i] = h;
  ((ushort4*)lo)[i] = l;
}

// ---------------- split helpers ----------------
__global__ void split_f4(const float* __restrict__ in, ushort_t* __restrict__ hi,
                         ushort_t* __restrict__ lo, int n4){
  int i = blockIdx.x*256 + threadIdx.x;
  if (i >= n4) return;
  float4 v = ((const float4*)in)[i];
  ushort4 h, l;
  split2(v.x, h.x, l.x); split2(v.y, h.y, l.y);
  split2(v.z, h.z, l.z); split2(v.w, h.w, l.w);
  ((ushort4*)hi)[i] = h;
  ((ushort4*)lo)[i] = l;
}

// W[K][M] fp32 -> transposed split WtHi/WtLo[M][K] bf16
__global__ void wsplit(const float* __restrict__ W, ushort_t* __restrict__ hiT,
                       ushort_t* __restrict__ loT, int K, int M){
  int i = blockIdx.x*256 + threadIdx.x;
  if (i >= K*M) return;
  int k = i / M, m = i % M;
  ushort_t h, l;
  split2(W[i], h, l);
  hiT[(size_t)m*K + k] = h;
  loT[(size_t)m*K + k] = l;
}

// ---------------- bf16x3 split MFMA GEMM ----------------
// C[n,M] = (Ahi+Alo)[n,K] @ (Bhi+Blo)^T  with B stored transposed [M][K].
// ACT: 0 none->Cf ; 1 bias+leaky ; 2 bias. SPLIT_OUT: write Chi/Clo instead of Cf.
// LDS tile: [row][32k] bf16, 64B/row as four 16B chunks; chunk index XOR-swizzled by
// (row>>1)&3 so frag ds_read_b128s are <=2-way bank-aliased (free, m136) while staging
// stays contiguous for global_load_lds (wave-uniform base + lane*16, m104/m108).
template<int BM, int BN, int WM, int WN, int ACT, int SPLIT_OUT>
__global__ __launch_bounds__(256) void gemm_mfma(
    const ushort_t* __restrict__ Ahi_g, const ushort_t* __restrict__ Alo_g,
    const ushort_t* __restrict__ Bhi_g, const ushort_t* __restrict__ Blo_g,
    const float* __restrict__ bias,
    float* __restrict__ Cf, ushort_t* __restrict__ Chi, ushort_t* __restrict__ Clo,
    int nrows, int K, int M){
  constexpr int FI = WM/16, FJ = WN/16;
  constexpr int WCOLS = BN/WN;
  __shared__ ushort_t sAhi[BM*32];
  __shared__ ushort_t sAlo[BM*32];
  __shared__ ushort_t sBhi[BN*32];
  __shared__ ushort_t sBlo[BN*32];
  const int tid  = threadIdx.x;
  const int wave = tid >> 6;
  const int lane = tid & 63;
  const int r0 = blockIdx.x * BM;
  const int c0 = blockIdx.y * BN;
  const int wr0 = (wave / WCOLS) * WM;
  const int wc0 = (wave % WCOLS) * WN;
  const int m = lane & 15, q = lane >> 4;

  v4f acc[FI][FJ];
#pragma unroll
  for (int i = 0; i < FI; ++i)
#pragma unroll
    for (int j = 0; j < FJ; ++j) acc[i][j] = (v4f){0.f,0.f,0.f,0.f};

  const int srow = lane >> 2;                        // row within 16-row chunk
  const int kqlog = (lane & 3) ^ ((srow >> 1) & 3);  // swizzled logical 16B chunk
  const int fsw = (q ^ ((m >> 1) & 3)) * 8;          // frag read: swizzled k elem offset

  for (int kt = 0; kt < K; kt += 32){
#pragma unroll
    for (int c = 0; c < BM/64; ++c){                 // each wave stages BM/64 16-row A-chunks
      int cc = c*4 + wave;
      int gr = r0 + cc*16 + srow;
      gr = min(gr, nrows - 1);
      size_t go = (size_t)gr*K + kt + kqlog*8;
      gload16(Ahi_g + go, &sAhi[cc*512]);
      gload16(Alo_g + go, &sAlo[cc*512]);
    }
    for (int cc = wave; cc < BN/16; cc += 4){
      int gr = c0 + cc*16 + srow;
      size_t go = (size_t)gr*K + kt + kqlog*8;
      gload16(Bhi_g + go, &sBhi[cc*512]);
      gload16(Blo_g + go, &sBlo[cc*512]);
    }
    __syncthreads();   // drains vmcnt (global_load_lds) per barrier semantics

    v8s ah[FI], al[FI], bh[FJ], bl[FJ];
#pragma unroll
    for (int i = 0; i < FI; ++i){
      int off = (wr0 + i*16 + m)*32 + fsw;
      ah[i] = *(const v8s*)&sAhi[off];
      al[i] = *(const v8s*)&sAlo[off];
    }
#pragma unroll
    for (int j = 0; j < FJ; ++j){
      int off = (wc0 + j*16 + m)*32 + fsw;
      bh[j] = *(const v8s*)&sBhi[off];
      bl[j] = *(const v8s*)&sBlo[off];
    }
#pragma unroll
    for (int i = 0; i < FI; ++i)
#pragma unroll
      for (int j = 0; j < FJ; ++j){
        acc[i][j] = __builtin_amdgcn_mfma_f32_16x16x32_bf16(ah[i], bh[j], acc[i][j], 0, 0, 0);
        acc[i][j] = __builtin_amdgcn_mfma_f32_16x16x32_bf16(ah[i], bl[j], acc[i][j], 0, 0, 0);
        acc[i][j] = __builtin_amdgcn_mfma_f32_16x16x32_bf16(al[i], bh[j], acc[i][j], 0, 0, 0);
      }
    __syncthreads();
  }

  // epilogue: C/D layout col = lane&15, row = (lane>>4)*4 + reg  [m89/m91]
#pragma unroll
  for (int i = 0; i < FI; ++i){
#pragma unroll
    for (int j = 0; j < FJ; ++j){
      int col = c0 + wc0 + j*16 + m;
      float bv = (ACT >= 1) ? bias[col] : 0.f;
#pragma unroll
      for (int r = 0; r < 4; ++r){
        int row = r0 + wr0 + i*16 + q*4 + r;
        if (row >= nrows) continue;
        float v = acc[i][j][r] + bv;
        if (ACT == 1) v = lk(v);
        size_t o = (size_t)row*M + col;
        if (SPLIT_OUT){
          ushort_t h, l; split2(v, h, l);
          Chi[o] = h; Clo[o] = l;
        } else {
          Cf[o] = v;
        }
      }
    }
  }
}

// ---------------- launch ----------------
extern "C" void kernel_launch(void* const* d_in, const int* in_sizes, int n_in,
                              void* d_out, int out_size, void* d_ws, size_t ws_size,
                              hipStream_t stream){
  const float* x   = (const float*)d_in[0];
  const int*   ei  = (const int*)  d_in[1];
  const float* ew  = (const float*)d_in[2];
  const float* W1  = (const float*)d_in[3];
  const float* b1  = (const float*)d_in[4];
  const float* g1  = (const float*)d_in[5];
  const float* be1 = (const float*)d_in[6];
  const float* W2  = (const float*)d_in[7];
  const float* b2  = (const float*)d_in[8];
  const float* g2  = (const float*)d_in[9];
  const float* be2 = (const float*)d_in[10];
  const float* W3  = (const float*)d_in[11];
  const float* b3  = (const float*)d_in[12];
  const float* g3  = (const float*)d_in[13];
  const float* be3 = (const float*)d_in[14];
  const float* Wl1 = (const float*)d_in[15];
  const float* bl1 = (const float*)d_in[16];
  const float* Wl2 = (const float*)d_in[17];
  const float* bl2 = (const float*)d_in[18];
  const int* src = ei;
  const int* dst = ei + NE;

  // ---- workspace: 2-slot rotation, total ~219.8 MB (round-1 proven budget) ----
  char* p = (char*)d_ws;
  auto carve = [&](size_t bytes)->void*{
    void* r = (void*)p;
    p += (bytes + 255) & ~(size_t)255;
    return r;
  };
  float*    dinv    = (float*)   carve((size_t)NN*4);
  int*      rp      = (int*)     carve((size_t)(NN+1)*4);
  int*      fill    = (int*)     carve((size_t)NN*4);    // counts, then cursor
  int*      bsum    = (int*)     carve(256*4);
  float*    stats   = (float*)   carve(1024*4);
  int*      csr_src = (int*)     carve((size_t)NE*4);
  float*    csr_w   = (float*)   carve((size_t)NE*4);
  float*    S1      = (float*)   carve((size_t)NN*256*4);   // 102.4 MB slot
  float*    S2      = (float*)   carve((size_t)NN*256*4);   // 102.4 MB slot
  ushort_t* W1tH    = (ushort_t*)carve(128*256*2);
  ushort_t* W1tL    = (ushort_t*)carve(128*256*2);
  ushort_t* W2tH    = (ushort_t*)carve(256*256*2);
  ushort_t* W2tL    = (ushort_t*)carve(256*256*2);
  ushort_t* W3tH    = (ushort_t*)carve(256*256*2);
  ushort_t* W3tL    = (ushort_t*)carve(256*256*2);
  ushort_t* Wl1tH   = (ushort_t*)carve(256*256*2);
  ushort_t* Wl1tL   = (ushort_t*)carve(256*256*2);
  ushort_t* Wl2tH   = (ushort_t*)carve(256*32*2);
  ushort_t* Wl2tL   = (ushort_t*)carve(256*32*2);

  // split views of the two slots (hi array then lo array within one slot)
  ushort_t* S1h256 = (ushort_t*)S1;  ushort_t* S1l256 = S1h256 + (size_t)NN*256;
  ushort_t* S2h256 = (ushort_t*)S2;  ushort_t* S2l256 = S2h256 + (size_t)NN*256;
  ushort_t* S1h128 = (ushort_t*)S1;  ushort_t* S1l128 = S1h128 + (size_t)NN*128;  // x split (K=128)

  const int nb = (NN + 1023) / 1024;

  // graph preprocessing (shared by all 3 conv layers)
  init_nodes<<<(NN+255)/256, 256, 0, stream>>>(dinv, fill, NN);
  edge_deg<<<(NE+255)/256, 256, 0, stream>>>(dst, ew, dinv, fill, NE);
  finalize_dinv<<<(NN+255)/256, 256, 0, stream>>>(dinv, NN);
  scan_block<<<nb, 1024, 0, stream>>>(fill, rp, bsum, NN);
  scan_small<<<1, 128, 0, stream>>>(bsum, nb);
  scan_add<<<nb, 1024, 0, stream>>>(rp, fill, bsum, NN, NE);
  fill_csr_k<<<(NE+255)/256, 256, 0, stream>>>(src, dst, ew, dinv, fill, csr_src, csr_w, NE);

  // weight + input splits
  wsplit<<<(128*256+255)/256, 256, 0, stream>>>(W1,  W1tH,  W1tL,  128, 256);
  wsplit<<<(256*256+255)/256, 256, 0, stream>>>(W2,  W2tH,  W2tL,  256, 256);
  wsplit<<<(256*256+255)/256, 256, 0, stream>>>(W3,  W3tH,  W3tL,  256, 256);
  wsplit<<<(256*256+255)/256, 256, 0, stream>>>(Wl1, Wl1tH, Wl1tL, 256, 256);
  wsplit<<<(256*32 +255)/256, 256, 0, stream>>>(Wl2, Wl2tH, Wl2tL, 256, 32);
  split_f4<<<(NN*32+255)/256, 256, 0, stream>>>(x, S1h128, S1l128, NN*32);   // x -> S1 split

  dim3 gridBig((NN+127)/128, 2);
  dim3 gridOut((NN+127)/128, 1);

  auto run_bn = [&](const float* fin, ushort_t* hi, ushort_t* lo,
                    const float* g, const float* be){
    zero_stats<<<1, 512, 0, stream>>>(stats);
    bn_partial<<<(NN+255)/256, 256, 0, stream>>>(fin, stats, NN);
    bn_final<<<1, 256, 0, stream>>>(stats, g, be, NN);
    bn_apply_split<<<(int)(((size_t)NN*64 + 255)/256), 256, 0, stream>>>(fin, stats, hi, lo, NN);
  };

  // conv1: S1(split x) -> S2 fp32 ; spmm S2 -> S1 fp32 ; bn S1 -> S2 split
  gemm_mfma<128,128,64,64,0,0><<<gridBig, 256, 0, stream>>>(
      S1h128, S1l128, W1tH, W1tL, nullptr, S2, nullptr, nullptr, NN, 128, 256);
  spmm_kern<<<(NN+3)/4, 256, 0, stream>>>(S2, rp, csr_src, csr_w, dinv, b1, S1, NN);
  run_bn(S1, S2h256, S2l256, g1, be1);

  // conv2: S2(split) -> S1 fp32 ; spmm S1 -> S2 fp32 ; bn S2 -> S1 split
  gemm_mfma<128,128,64,64,0,0><<<gridBig, 256, 0, stream>>>(
      S2h256, S2l256, W2tH, W2tL, nullptr, S1, nullptr, nullptr, NN, 256, 256);
  spmm_kern<<<(NN+3)/4, 256, 0, stream>>>(S1, rp, csr_src, csr_w, dinv, b2, S2, NN);
  run_bn(S2, S1h256, S1l256, g2, be2);

  // conv3: S1(split) -> S2 fp32 ; spmm S2 -> S1 fp32 ; bn S1 -> S2 split
  gemm_mfma<128,128,64,64,0,0><<<gridBig, 256, 0, stream>>>(
      S1h256, S1l256, W3tH, W3tL, nullptr, S2, nullptr, nullptr, NN, 256, 256);
  spmm_kern<<<(NN+3)/4, 256, 0, stream>>>(S2, rp, csr_src, csr_w, dinv, b3, S1, NN);
  run_bn(S1, S2h256, S2l256, g3, be3);

  // head: leaky(h @ Wl1 + bl1) -> S1 split ; then @ Wl2 + bl2 -> d_out
  gemm_mfma<128,128,64,64,1,1><<<gridBig, 256, 0, stream>>>(
      S2h256, S2l256, Wl1tH, Wl1tL, bl1, nullptr, S1h256, S1l256, NN, 256, 256);
  gemm_mfma<128,32,32,32,2,0><<<gridOut, 256, 0, stream>>>(
      S1h256, S1l256, Wl2tH, Wl2tL, bl2, (float*)d_out, nullptr, nullptr, NN, 256, 32);
}

// Round 4
// 1591.397 us; speedup vs baseline: 1.3341x; 1.0825x over previous
//
#include <hip/hip_runtime.h>

#define NN 100000
#define NE 1600000
#define EPS_BN 1e-5f

typedef unsigned short ushort_t;
typedef short v8s __attribute__((ext_vector_type(8)));   // 8 bf16 (4 VGPR)
typedef float v4f __attribute__((ext_vector_type(4)));   // 4 fp32 acc

__device__ __forceinline__ float lk(float x){ return x >= 0.f ? x : 0.1f*x; }

__device__ __forceinline__ ushort_t f2bf(float x){
  unsigned u = __float_as_uint(x);
  unsigned r = (u + 0x7fffu + ((u >> 16) & 1u)) >> 16;
  return (ushort_t)r;
}
__device__ __forceinline__ float bf2f(ushort_t h){
  return __uint_as_float(((unsigned)h) << 16);
}
__device__ __forceinline__ void split2(float x, ushort_t& hi, ushort_t& lo){
  hi = f2bf(x);
  lo = f2bf(x - bf2f(hi));
}

// async 16B global->LDS (lds dst is wave-uniform base; HW adds lane*16)
__device__ __forceinline__ void gload16(const ushort_t* g, ushort_t* l){
  __builtin_amdgcn_global_load_lds((const __attribute__((address_space(1))) void*)g,
                                   (__attribute__((address_space(3))) void*)l, 16, 0, 0);
}

// ---------------- degree / dinv ----------------
__global__ void init_nodes(float* __restrict__ deg, int* __restrict__ cnt, int n){
  int i = blockIdx.x*256 + threadIdx.x;
  if (i < n){ deg[i] = 1.0f; cnt[i] = 0; }
}

__global__ void edge_deg(const int* __restrict__ dst, const float* __restrict__ ew,
                         float* __restrict__ deg, int* __restrict__ cnt, int e){
  int i = blockIdx.x*256 + threadIdx.x;
  if (i < e){
    int d = dst[i];
    atomicAdd(&deg[d], ew[i]);
    atomicAdd(&cnt[d], 1);
  }
}

__global__ void finalize_dinv(float* __restrict__ deg, int n){
  int i = blockIdx.x*256 + threadIdx.x;
  if (i < n) deg[i] = rsqrtf(deg[i]);
}

// ---------------- exclusive scan (3-kernel) ----------------
__global__ __launch_bounds__(1024) void scan_block(const int* __restrict__ in, int* __restrict__ out,
                                                   int* __restrict__ bsum, int n){
  __shared__ int s[1024];
  int t = threadIdx.x;
  int i = blockIdx.x*1024 + t;
  int v = (i < n) ? in[i] : 0;
  s[t] = v; __syncthreads();
  for (int off = 1; off < 1024; off <<= 1){
    int x = (t >= off) ? s[t-off] : 0;
    __syncthreads();
    s[t] += x;
    __syncthreads();
  }
  if (i < n) out[i] = s[t] - v;
  if (t == 1023) bsum[blockIdx.x] = s[1023];
}

__global__ void scan_small(int* __restrict__ bsum, int nb){
  __shared__ int s[128];
  int t = threadIdx.x;
  int v = (t < nb) ? bsum[t] : 0;
  s[t] = v; __syncthreads();
  for (int off = 1; off < 128; off <<= 1){
    int x = (t >= off) ? s[t-off] : 0;
    __syncthreads();
    s[t] += x;
    __syncthreads();
  }
  if (t < nb) bsum[t] = s[t] - v;
}

__global__ __launch_bounds__(1024) void scan_add(int* __restrict__ rp, int* __restrict__ fill,
                                                 const int* __restrict__ bsum, int n, int etot){
  int i = blockIdx.x*1024 + threadIdx.x;
  if (i < n){
    int v = rp[i] + bsum[blockIdx.x];
    rp[i] = v;
    fill[i] = v;
  }
  if (i == 0) rp[n] = etot;
}

// ---------------- CSR fill ----------------
__global__ void fill_csr_k(const int* __restrict__ src, const int* __restrict__ dst,
                           const float* __restrict__ ew, const float* __restrict__ dinv,
                           int* __restrict__ fill, int* __restrict__ csr_src,
                           float* __restrict__ csr_w, int e){
  int i = blockIdx.x*256 + threadIdx.x;
  if (i >= e) return;
  int s = src[i], d = dst[i];
  int pos = atomicAdd(&fill[d], 1);
  csr_src[pos] = s;
  csr_w[pos] = dinv[s] * ew[i] * dinv[d];
}

// ---------------- SpMM half-width pass (128 channels), gather by destination ----------------
// out[node, coff:coff+128] = c0*h[node,...] + bias + sum_e w_e * h[src_e, ...]
// One wave64 per node, float2/lane. 4-deep unrolled gathers (independent, pipelined).
// Per-pass gather working set = NN*128*4B = 51.2 MB -> L3-resident.
__global__ __launch_bounds__(256) void spmm_half(const float* __restrict__ h,
    const int* __restrict__ rp, const int* __restrict__ csr_src, const float* __restrict__ csr_w,
    const float* __restrict__ dinv, const float* __restrict__ bias,
    float* __restrict__ out, int n, int stride, int coff){
  int node = blockIdx.x*4 + (threadIdx.x >> 6);
  node = __builtin_amdgcn_readfirstlane(node);   // wave-uniform -> scalarize CSR loads
  if (node >= n) return;
  int lane = threadIdx.x & 63;
  const float* hb = h + coff + lane*2;
  float di = dinv[node];
  float c0 = di * di;
  float2 hv = *(const float2*)(hb + (size_t)node*stride);
  float ax, ay;
  if (bias){
    float2 bb = *(const float2*)(bias + coff + lane*2);
    ax = fmaf(c0, hv.x, bb.x);
    ay = fmaf(c0, hv.y, bb.y);
  } else {
    ax = c0 * hv.x;
    ay = c0 * hv.y;
  }
  int p = rp[node], pend = rp[node+1];
  for (; p + 4 <= pend; p += 4){
    int s0 = csr_src[p],   s1 = csr_src[p+1], s2 = csr_src[p+2], s3 = csr_src[p+3];
    float w0 = csr_w[p],   w1 = csr_w[p+1],   w2 = csr_w[p+2],   w3 = csr_w[p+3];
    float2 v0 = *(const float2*)(hb + (size_t)s0*stride);
    float2 v1 = *(const float2*)(hb + (size_t)s1*stride);
    float2 v2 = *(const float2*)(hb + (size_t)s2*stride);
    float2 v3 = *(const float2*)(hb + (size_t)s3*stride);
    ax = fmaf(w0, v0.x, ax); ay = fmaf(w0, v0.y, ay);
    ax = fmaf(w1, v1.x, ax); ay = fmaf(w1, v1.y, ay);
    ax = fmaf(w2, v2.x, ax); ay = fmaf(w2, v2.y, ay);
    ax = fmaf(w3, v3.x, ax); ay = fmaf(w3, v3.y, ay);
  }
  for (; p < pend; ++p){
    int s = csr_src[p];
    float w = csr_w[p];
    float2 v = *(const float2*)(hb + (size_t)s*stride);
    ax = fmaf(w, v.x, ax); ay = fmaf(w, v.y, ay);
  }
  *(float2*)(out + (size_t)node*stride + coff + lane*2) = make_float2(ax, ay);
}

// ---------------- BatchNorm ----------------
__global__ void zero_stats(float* __restrict__ stats){
  stats[threadIdx.x] = 0.f;   // 512 threads
}

__global__ __launch_bounds__(256) void bn_partial(const float* __restrict__ a,
                                                  float* __restrict__ stats, int n){
  int c = threadIdx.x;
  int r0 = blockIdx.x * 256;
  int rend = min(r0 + 256, n);
  float s = 0.f, s2 = 0.f;
  for (int r = r0; r < rend; ++r){
    float v = a[(size_t)r*256 + c];
    s += v;
    s2 = fmaf(v, v, s2);
  }
  atomicAdd(&stats[c], s);
  atomicAdd(&stats[256 + c], s2);
}

__global__ void bn_final(float* __restrict__ stats, const float* __restrict__ g,
                         const float* __restrict__ be, int n){
  int c = threadIdx.x;
  float inv_n = 1.0f / (float)n;
  float mean = stats[c] * inv_n;
  float var  = fmaxf(stats[256 + c] * inv_n - mean*mean, 0.f);
  float sc   = g[c] * rsqrtf(var + EPS_BN);
  stats[512 + c] = sc;
  stats[768 + c] = be[c] - mean * sc;
}

// bn scale/shift + leaky, emit hi/lo bf16 split directly (feeds next MFMA GEMM)
__global__ __launch_bounds__(256) void bn_apply_split(const float* __restrict__ a,
    const float* __restrict__ stats, ushort_t* __restrict__ hi, ushort_t* __restrict__ lo, int n){
  size_t i = (size_t)blockIdx.x*256 + threadIdx.x;   // one float4 per thread
  if (i >= (size_t)n*64) return;
  int c4 = (int)(i & 63);
  float4 v  = ((const float4*)a)[i];
  float4 sc = ((const float4*)(stats + 512))[c4];
  float4 sh = ((const float4*)(stats + 768))[c4];
  v.x = lk(fmaf(v.x, sc.x, sh.x));
  v.y = lk(fmaf(v.y, sc.y, sh.y));
  v.z = lk(fmaf(v.z, sc.z, sh.z));
  v.w = lk(fmaf(v.w, sc.w, sh.w));
  ushort4 h, l;
  split2(v.x, h.x, l.x); split2(v.y, h.y, l.y);
  split2(v.z, h.z, l.z); split2(v.w, h.w, l.w);
  ((ushort4*)hi)[i] = h;
  ((ushort4*)lo)[i] = l;
}

// ---------------- split helpers ----------------
__global__ void split_f4(const float* __restrict__ in, ushort_t* __restrict__ hi,
                         ushort_t* __restrict__ lo, int n4){
  int i = blockIdx.x*256 + threadIdx.x;
  if (i >= n4) return;
  float4 v = ((const float4*)in)[i];
  ushort4 h, l;
  split2(v.x, h.x, l.x); split2(v.y, h.y, l.y);
  split2(v.z, h.z, l.z); split2(v.w, h.w, l.w);
  ((ushort4*)hi)[i] = h;
  ((ushort4*)lo)[i] = l;
}

// W[K][M] fp32 -> transposed split WtHi/WtLo[M][K] bf16
__global__ void wsplit(const float* __restrict__ W, ushort_t* __restrict__ hiT,
                       ushort_t* __restrict__ loT, int K, int M){
  int i = blockIdx.x*256 + threadIdx.x;
  if (i >= K*M) return;
  int k = i / M, m = i % M;
  ushort_t h, l;
  split2(W[i], h, l);
  hiT[(size_t)m*K + k] = h;
  loT[(size_t)m*K + k] = l;
}

// ---------------- bf16x3 split MFMA GEMM ----------------
// C[n,M] = (Ahi+Alo)[n,K] @ (Bhi+Blo)^T  with B stored transposed [M][K].
// ACT: 0 none->Cf ; 1 bias+leaky ; 2 bias. SPLIT_OUT: write Chi/Clo instead of Cf.
template<int BM, int BN, int WM, int WN, int ACT, int SPLIT_OUT>
__global__ __launch_bounds__(256) void gemm_mfma(
    const ushort_t* __restrict__ Ahi_g, const ushort_t* __restrict__ Alo_g,
    const ushort_t* __restrict__ Bhi_g, const ushort_t* __restrict__ Blo_g,
    const float* __restrict__ bias,
    float* __restrict__ Cf, ushort_t* __restrict__ Chi, ushort_t* __restrict__ Clo,
    int nrows, int K, int M){
  constexpr int FI = WM/16, FJ = WN/16;
  constexpr int WCOLS = BN/WN;
  __shared__ ushort_t sAhi[BM*32];
  __shared__ ushort_t sAlo[BM*32];
  __shared__ ushort_t sBhi[BN*32];
  __shared__ ushort_t sBlo[BN*32];
  const int tid  = threadIdx.x;
  const int wave = tid >> 6;
  const int lane = tid & 63;
  const int r0 = blockIdx.x * BM;
  const int c0 = blockIdx.y * BN;
  const int wr0 = (wave / WCOLS) * WM;
  const int wc0 = (wave % WCOLS) * WN;
  const int m = lane & 15, q = lane >> 4;

  v4f acc[FI][FJ];
#pragma unroll
  for (int i = 0; i < FI; ++i)
#pragma unroll
    for (int j = 0; j < FJ; ++j) acc[i][j] = (v4f){0.f,0.f,0.f,0.f};

  const int srow = lane >> 2;                        // row within 16-row chunk
  const int kqlog = (lane & 3) ^ ((srow >> 1) & 3);  // swizzled logical 16B chunk
  const int fsw = (q ^ ((m >> 1) & 3)) * 8;          // frag read: swizzled k elem offset

  for (int kt = 0; kt < K; kt += 32){
#pragma unroll
    for (int c = 0; c < BM/64; ++c){                 // each wave stages BM/64 16-row A-chunks
      int cc = c*4 + wave;
      int gr = r0 + cc*16 + srow;
      gr = min(gr, nrows - 1);
      size_t go = (size_t)gr*K + kt + kqlog*8;
      gload16(Ahi_g + go, &sAhi[cc*512]);
      gload16(Alo_g + go, &sAlo[cc*512]);
    }
    for (int cc = wave; cc < BN/16; cc += 4){
      int gr = c0 + cc*16 + srow;
      size_t go = (size_t)gr*K + kt + kqlog*8;
      gload16(Bhi_g + go, &sBhi[cc*512]);
      gload16(Blo_g + go, &sBlo[cc*512]);
    }
    __syncthreads();   // drains vmcnt (global_load_lds) per barrier semantics

    v8s ah[FI], al[FI], bh[FJ], bl[FJ];
#pragma unroll
    for (int i = 0; i < FI; ++i){
      int off = (wr0 + i*16 + m)*32 + fsw;
      ah[i] = *(const v8s*)&sAhi[off];
      al[i] = *(const v8s*)&sAlo[off];
    }
#pragma unroll
    for (int j = 0; j < FJ; ++j){
      int off = (wc0 + j*16 + m)*32 + fsw;
      bh[j] = *(const v8s*)&sBhi[off];
      bl[j] = *(const v8s*)&sBlo[off];
    }
#pragma unroll
    for (int i = 0; i < FI; ++i)
#pragma unroll
      for (int j = 0; j < FJ; ++j){
        acc[i][j] = __builtin_amdgcn_mfma_f32_16x16x32_bf16(ah[i], bh[j], acc[i][j], 0, 0, 0);
        acc[i][j] = __builtin_amdgcn_mfma_f32_16x16x32_bf16(ah[i], bl[j], acc[i][j], 0, 0, 0);
        acc[i][j] = __builtin_amdgcn_mfma_f32_16x16x32_bf16(al[i], bh[j], acc[i][j], 0, 0, 0);
      }
    __syncthreads();
  }

  // epilogue: C/D layout col = lane&15, row = (lane>>4)*4 + reg  [m89/m91]
#pragma unroll
  for (int i = 0; i < FI; ++i){
#pragma unroll
    for (int j = 0; j < FJ; ++j){
      int col = c0 + wc0 + j*16 + m;
      float bv = (ACT >= 1) ? bias[col] : 0.f;
#pragma unroll
      for (int r = 0; r < 4; ++r){
        int row = r0 + wr0 + i*16 + q*4 + r;
        if (row >= nrows) continue;
        float v = acc[i][j][r] + bv;
        if (ACT == 1) v = lk(v);
        size_t o = (size_t)row*M + col;
        if (SPLIT_OUT){
          ushort_t h, l; split2(v, h, l);
          Chi[o] = h; Clo[o] = l;
        } else {
          Cf[o] = v;
        }
      }
    }
  }
}

// ---------------- launch ----------------
extern "C" void kernel_launch(void* const* d_in, const int* in_sizes, int n_in,
                              void* d_out, int out_size, void* d_ws, size_t ws_size,
                              hipStream_t stream){
  const float* x   = (const float*)d_in[0];
  const int*   ei  = (const int*)  d_in[1];
  const float* ew  = (const float*)d_in[2];
  const float* W1  = (const float*)d_in[3];
  const float* b1  = (const float*)d_in[4];
  const float* g1  = (const float*)d_in[5];
  const float* be1 = (const float*)d_in[6];
  const float* W2  = (const float*)d_in[7];
  const float* b2  = (const float*)d_in[8];
  const float* g2  = (const float*)d_in[9];
  const float* be2 = (const float*)d_in[10];
  const float* W3  = (const float*)d_in[11];
  const float* b3  = (const float*)d_in[12];
  const float* g3  = (const float*)d_in[13];
  const float* be3 = (const float*)d_in[14];
  const float* Wl1 = (const float*)d_in[15];
  const float* bl1 = (const float*)d_in[16];
  const float* Wl2 = (const float*)d_in[17];
  const float* bl2 = (const float*)d_in[18];
  const int* src = ei;
  const int* dst = ei + NE;

  // ---- workspace: 2-slot rotation, total ~220 MB (proven budget) ----
  char* p = (char*)d_ws;
  auto carve = [&](size_t bytes)->void*{
    void* r = (void*)p;
    p += (bytes + 255) & ~(size_t)255;
    return r;
  };
  float*    dinv    = (float*)   carve((size_t)NN*4);
  int*      rp      = (int*)     carve((size_t)(NN+1)*4);
  int*      fill    = (int*)     carve((size_t)NN*4);    // counts, then cursor
  int*      bsum    = (int*)     carve(256*4);
  float*    stats   = (float*)   carve(1024*4);
  int*      csr_src = (int*)     carve((size_t)NE*4);
  float*    csr_w   = (float*)   carve((size_t)NE*4);
  float*    S1      = (float*)   carve((size_t)NN*256*4);   // 102.4 MB slot
  float*    S2      = (float*)   carve((size_t)NN*256*4);   // 102.4 MB slot
  ushort_t* W1tH    = (ushort_t*)carve(128*256*2);
  ushort_t* W1tL    = (ushort_t*)carve(128*256*2);
  ushort_t* W2tH    = (ushort_t*)carve(256*256*2);
  ushort_t* W2tL    = (ushort_t*)carve(256*256*2);
  ushort_t* W3tH    = (ushort_t*)carve(256*256*2);
  ushort_t* W3tL    = (ushort_t*)carve(256*256*2);
  ushort_t* Wl1tH   = (ushort_t*)carve(256*256*2);
  ushort_t* Wl1tL   = (ushort_t*)carve(256*256*2);
  ushort_t* Wl2tH   = (ushort_t*)carve(256*32*2);
  ushort_t* Wl2tL   = (ushort_t*)carve(256*32*2);

  // split views of the two slots (hi array then lo array within one slot)
  ushort_t* S1h256 = (ushort_t*)S1;  ushort_t* S1l256 = S1h256 + (size_t)NN*256;
  ushort_t* S2h256 = (ushort_t*)S2;  ushort_t* S2l256 = S2h256 + (size_t)NN*256;
  ushort_t* S1h128 = (ushort_t*)S1;  ushort_t* S1l128 = S1h128 + (size_t)NN*128;  // ax split (K=128)

  const int nb = (NN + 1023) / 1024;
  const int spmm_blocks = (NN + 3) / 4;

  // graph preprocessing (shared by all 3 conv layers)
  init_nodes<<<(NN+255)/256, 256, 0, stream>>>(dinv, fill, NN);
  edge_deg<<<(NE+255)/256, 256, 0, stream>>>(dst, ew, dinv, fill, NE);
  finalize_dinv<<<(NN+255)/256, 256, 0, stream>>>(dinv, NN);
  scan_block<<<nb, 1024, 0, stream>>>(fill, rp, bsum, NN);
  scan_small<<<1, 128, 0, stream>>>(bsum, nb);
  scan_add<<<nb, 1024, 0, stream>>>(rp, fill, bsum, NN, NE);
  fill_csr_k<<<(NE+255)/256, 256, 0, stream>>>(src, dst, ew, dinv, fill, csr_src, csr_w, NE);

  // weight splits
  wsplit<<<(128*256+255)/256, 256, 0, stream>>>(W1,  W1tH,  W1tL,  128, 256);
  wsplit<<<(256*256+255)/256, 256, 0, stream>>>(W2,  W2tH,  W2tL,  256, 256);
  wsplit<<<(256*256+255)/256, 256, 0, stream>>>(W3,  W3tH,  W3tL,  256, 256);
  wsplit<<<(256*256+255)/256, 256, 0, stream>>>(Wl1, Wl1tH, Wl1tL, 256, 256);
  wsplit<<<(256*32 +255)/256, 256, 0, stream>>>(Wl2, Wl2tH, Wl2tL, 256, 32);

  dim3 gridBig((NN+127)/128, 2);
  dim3 gridOut((NN+127)/128, 1);

  auto run_bn = [&](const float* fin, ushort_t* hi, ushort_t* lo,
                    const float* g, const float* be){
    zero_stats<<<1, 512, 0, stream>>>(stats);
    bn_partial<<<(NN+255)/256, 256, 0, stream>>>(fin, stats, NN);
    bn_final<<<1, 256, 0, stream>>>(stats, g, be, NN);
    bn_apply_split<<<(int)(((size_t)NN*64 + 255)/256), 256, 0, stream>>>(fin, stats, hi, lo, NN);
  };

  // conv1 (aggregate-first: (A~ x) W1 + b1 == A~ (x W1) + b1):
  //   spmm on x (128 ch, one pass) -> S2[:,0:128] region ; split -> S1 ; gemm+b1 -> S2 fp32
  spmm_half<<<spmm_blocks, 256, 0, stream>>>(x, rp, csr_src, csr_w, dinv, nullptr,
                                             S2, NN, 128, 0);
  split_f4<<<(NN*32+255)/256, 256, 0, stream>>>(S2, S1h128, S1l128, NN*32);
  gemm_mfma<128,128,64,64,2,0><<<gridBig, 256, 0, stream>>>(
      S1h128, S1l128, W1tH, W1tL, b1, S2, nullptr, nullptr, NN, 128, 256);
  run_bn(S2, S1h256, S1l256, g1, be1);

  // conv2: gemm S1(split) -> S2 fp32 ; spmm 2 half passes S2 -> S1 ; bn S1 -> S2 split
  gemm_mfma<128,128,64,64,0,0><<<gridBig, 256, 0, stream>>>(
      S1h256, S1l256, W2tH, W2tL, nullptr, S2, nullptr, nullptr, NN, 256, 256);
  spmm_half<<<spmm_blocks, 256, 0, stream>>>(S2, rp, csr_src, csr_w, dinv, b2, S1, NN, 256, 0);
  spmm_half<<<spmm_blocks, 256, 0, stream>>>(S2, rp, csr_src, csr_w, dinv, b2, S1, NN, 256, 128);
  run_bn(S1, S2h256, S2l256, g2, be2);

  // conv3: gemm S2(split) -> S1 fp32 ; spmm S1 -> S2 ; bn S2 -> S1 split
  gemm_mfma<128,128,64,64,0,0><<<gridBig, 256, 0, stream>>>(
      S2h256, S2l256, W3tH, W3tL, nullptr, S1, nullptr, nullptr, NN, 256, 256);
  spmm_half<<<spmm_blocks, 256, 0, stream>>>(S1, rp, csr_src, csr_w, dinv, b3, S2, NN, 256, 0);
  spmm_half<<<spmm_blocks, 256, 0, stream>>>(S1, rp, csr_src, csr_w, dinv, b3, S2, NN, 256, 128);
  run_bn(S2, S1h256, S1l256, g3, be3);

  // head: leaky(h @ Wl1 + bl1) -> S2 split ; then @ Wl2 + bl2 -> d_out
  gemm_mfma<128,128,64,64,1,1><<<gridBig, 256, 0, stream>>>(
      S1h256, S1l256, Wl1tH, Wl1tL, bl1, nullptr, S2h256, S2l256, NN, 256, 256);
  gemm_mfma<128,32,32,32,2,0><<<gridOut, 256, 0, stream>>>(
      S2h256, S2l256, Wl2tH, Wl2tL, bl2, (float*)d_out, nullptr, nullptr, NN, 256, 32);
}

// Round 5
// 1488.080 us; speedup vs baseline: 1.4267x; 1.0694x over previous
//
#include <hip/hip_runtime.h>

#define NN 100000
#define NE 1600000
#define EPS_BN 1e-5f

typedef unsigned short ushort_t;
typedef unsigned long long u64;
typedef short v8s __attribute__((ext_vector_type(8)));   // 8 bf16 (4 VGPR)
typedef float v4f __attribute__((ext_vector_type(4)));   // 4 fp32 acc

__device__ __forceinline__ float lk(float x){ return x >= 0.f ? x : 0.1f*x; }

__device__ __forceinline__ ushort_t f2bf(float x){
  unsigned u = __float_as_uint(x);
  unsigned r = (u + 0x7fffu + ((u >> 16) & 1u)) >> 16;
  return (ushort_t)r;
}
__device__ __forceinline__ float bf2f(ushort_t h){
  return __uint_as_float(((unsigned)h) << 16);
}
__device__ __forceinline__ void split2(float x, ushort_t& hi, ushort_t& lo){
  hi = f2bf(x);
  lo = f2bf(x - bf2f(hi));
}

// async 16B global->LDS (lds dst is wave-uniform base; HW adds lane*16)
__device__ __forceinline__ void gload16(const ushort_t* g, ushort_t* l){
  __builtin_amdgcn_global_load_lds((const __attribute__((address_space(1))) void*)g,
                                   (__attribute__((address_space(3))) void*)l, 16, 0, 0);
}

// ---------------- degree+count histogram: ONE packed u64 atomic per edge ----------------
// acc[d] += (1<<40) | round(ew * 2^26).  cnt = acc>>40 ; wdeg = (acc & (2^40-1)) * 2^-26.
// Max low-field sum: deg<=~100 edges * 2^26 ~ 2^33 << 2^40 -> no overflow into cnt field.
__global__ void zero_acc(u64* __restrict__ acc, int n){
  int i = blockIdx.x*256 + threadIdx.x;
  if (i < n) acc[i] = 0ull;
}

__global__ void edge_hist(const int* __restrict__ dst, const float* __restrict__ ew,
                          u64* __restrict__ acc, int e){
  int i = blockIdx.x*256 + threadIdx.x;
  if (i < e){
    int d = dst[i];
    unsigned fx = (unsigned)(ew[i] * 67108864.0f + 0.5f);   // 2^26 fixed point
    atomicAdd(&acc[d], (1ull << 40) | (u64)fx);
  }
}

__global__ void finalize_acc(const u64* __restrict__ acc, float* __restrict__ dinv,
                             int* __restrict__ cnt, int n){
  int i = blockIdx.x*256 + threadIdx.x;
  if (i < n){
    u64 v = acc[i];
    cnt[i] = (int)(v >> 40);
    double w = (double)(v & 0xFFFFFFFFFFull) * (1.0/67108864.0);
    dinv[i] = rsqrtf((float)(1.0 + w));   // +1 self loop
  }
}

// ---------------- exclusive scan (3-kernel) ----------------
__global__ __launch_bounds__(1024) void scan_block(const int* __restrict__ in, int* __restrict__ out,
                                                   int* __restrict__ bsum, int n){
  __shared__ int s[1024];
  int t = threadIdx.x;
  int i = blockIdx.x*1024 + t;
  int v = (i < n) ? in[i] : 0;
  s[t] = v; __syncthreads();
  for (int off = 1; off < 1024; off <<= 1){
    int x = (t >= off) ? s[t-off] : 0;
    __syncthreads();
    s[t] += x;
    __syncthreads();
  }
  if (i < n) out[i] = s[t] - v;
  if (t == 1023) bsum[blockIdx.x] = s[1023];
}

__global__ void scan_small(int* __restrict__ bsum, int nb){
  __shared__ int s[128];
  int t = threadIdx.x;
  int v = (t < nb) ? bsum[t] : 0;
  s[t] = v; __syncthreads();
  for (int off = 1; off < 128; off <<= 1){
    int x = (t >= off) ? s[t-off] : 0;
    __syncthreads();
    s[t] += x;
    __syncthreads();
  }
  if (t < nb) bsum[t] = s[t] - v;
}

__global__ __launch_bounds__(1024) void scan_add(int* __restrict__ rp, int* __restrict__ fill,
                                                 const int* __restrict__ bsum, int n, int etot){
  int i = blockIdx.x*1024 + threadIdx.x;
  if (i < n){
    int v = rp[i] + bsum[blockIdx.x];
    rp[i] = v;
    fill[i] = v;
  }
  if (i == 0) rp[n] = etot;
}

// ---------------- CSR fill: one scattered 8B store per edge ----------------
__global__ void fill_csr_k(const int* __restrict__ src, const int* __restrict__ dst,
                           const float* __restrict__ ew, const float* __restrict__ dinv,
                           int* __restrict__ fill, int2* __restrict__ csr_sw, int e){
  int i = blockIdx.x*256 + threadIdx.x;
  if (i >= e) return;
  int s = src[i], d = dst[i];
  int pos = atomicAdd(&fill[d], 1);
  float w = dinv[s] * ew[i] * dinv[d];
  csr_sw[pos] = make_int2(s, __float_as_int(w));
}

// ---------------- SpMM half-width pass (128 channels), gather by destination ----------------
// Per-pass gather working set = NN*128*4B = 51.2 MB -> L3-resident.
__global__ __launch_bounds__(256) void spmm_half(const float* __restrict__ h,
    const int* __restrict__ rp, const int2* __restrict__ csr_sw,
    const float* __restrict__ dinv, const float* __restrict__ bias,
    float* __restrict__ out, int n, int stride, int coff){
  int node = blockIdx.x*4 + (threadIdx.x >> 6);
  node = __builtin_amdgcn_readfirstlane(node);   // wave-uniform -> scalarize CSR loads
  if (node >= n) return;
  int lane = threadIdx.x & 63;
  const float* hb = h + coff + lane*2;
  float di = dinv[node];
  float c0 = di * di;
  float2 hv = *(const float2*)(hb + (size_t)node*stride);
  float ax, ay;
  if (bias){
    float2 bb = *(const float2*)(bias + coff + lane*2);
    ax = fmaf(c0, hv.x, bb.x);
    ay = fmaf(c0, hv.y, bb.y);
  } else {
    ax = c0 * hv.x;
    ay = c0 * hv.y;
  }
  int p = rp[node], pend = rp[node+1];
  for (; p + 4 <= pend; p += 4){
    int2 e0 = csr_sw[p],   e1 = csr_sw[p+1], e2 = csr_sw[p+2], e3 = csr_sw[p+3];
    float2 v0 = *(const float2*)(hb + (size_t)e0.x*stride);
    float2 v1 = *(const float2*)(hb + (size_t)e1.x*stride);
    float2 v2 = *(const float2*)(hb + (size_t)e2.x*stride);
    float2 v3 = *(const float2*)(hb + (size_t)e3.x*stride);
    float w0 = __int_as_float(e0.y), w1 = __int_as_float(e1.y);
    float w2 = __int_as_float(e2.y), w3 = __int_as_float(e3.y);
    ax = fmaf(w0, v0.x, ax); ay = fmaf(w0, v0.y, ay);
    ax = fmaf(w1, v1.x, ax); ay = fmaf(w1, v1.y, ay);
    ax = fmaf(w2, v2.x, ax); ay = fmaf(w2, v2.y, ay);
    ax = fmaf(w3, v3.x, ax); ay = fmaf(w3, v3.y, ay);
  }
  for (; p < pend; ++p){
    int2 e = csr_sw[p];
    float w = __int_as_float(e.y);
    float2 v = *(const float2*)(hb + (size_t)e.x*stride);
    ax = fmaf(w, v.x, ax); ay = fmaf(w, v.y, ay);
  }
  *(float2*)(out + (size_t)node*stride + coff + lane*2) = make_float2(ax, ay);
}

// ---------------- BatchNorm ----------------
__global__ void zero_stats(float* __restrict__ stats){
  stats[threadIdx.x] = 0.f;   // 512 threads
}

__global__ __launch_bounds__(256) void bn_partial(const float* __restrict__ a,
                                                  float* __restrict__ stats, int n){
  int c = threadIdx.x;
  int r0 = blockIdx.x * 256;
  int rend = min(r0 + 256, n);
  float s = 0.f, s2 = 0.f;
  for (int r = r0; r < rend; ++r){
    float v = a[(size_t)r*256 + c];
    s += v;
    s2 = fmaf(v, v, s2);
  }
  atomicAdd(&stats[c], s);
  atomicAdd(&stats[256 + c], s2);
}

__global__ void bn_final(float* __restrict__ stats, const float* __restrict__ g,
                         const float* __restrict__ be, int n){
  int c = threadIdx.x;
  float inv_n = 1.0f / (float)n;
  float mean = stats[c] * inv_n;
  float var  = fmaxf(stats[256 + c] * inv_n - mean*mean, 0.f);
  float sc   = g[c] * rsqrtf(var + EPS_BN);
  stats[512 + c] = sc;
  stats[768 + c] = be[c] - mean * sc;
}

// bn scale/shift + leaky, emit hi/lo bf16 split directly (feeds next MFMA GEMM)
__global__ __launch_bounds__(256) void bn_apply_split(const float* __restrict__ a,
    const float* __restrict__ stats, ushort_t* __restrict__ hi, ushort_t* __restrict__ lo, int n){
  size_t i = (size_t)blockIdx.x*256 + threadIdx.x;   // one float4 per thread
  if (i >= (size_t)n*64) return;
  int c4 = (int)(i & 63);
  float4 v  = ((const float4*)a)[i];
  float4 sc = ((const float4*)(stats + 512))[c4];
  float4 sh = ((const float4*)(stats + 768))[c4];
  v.x = lk(fmaf(v.x, sc.x, sh.x));
  v.y = lk(fmaf(v.y, sc.y, sh.y));
  v.z = lk(fmaf(v.z, sc.z, sh.z));
  v.w = lk(fmaf(v.w, sc.w, sh.w));
  ushort4 h, l;
  split2(v.x, h.x, l.x); split2(v.y, h.y, l.y);
  split2(v.z, h.z, l.z); split2(v.w, h.w, l.w);
  ((ushort4*)hi)[i] = h;
  ((ushort4*)lo)[i] = l;
}

// ---------------- split helpers ----------------
__global__ void split_f4(const float* __restrict__ in, ushort_t* __restrict__ hi,
                         ushort_t* __restrict__ lo, int n4){
  int i = blockIdx.x*256 + threadIdx.x;
  if (i >= n4) return;
  float4 v = ((const float4*)in)[i];
  ushort4 h, l;
  split2(v.x, h.x, l.x); split2(v.y, h.y, l.y);
  split2(v.z, h.z, l.z); split2(v.w, h.w, l.w);
  ((ushort4*)hi)[i] = h;
  ((ushort4*)lo)[i] = l;
}

// W[K][M] fp32 -> transposed split WtHi/WtLo[M][K] bf16
__global__ void wsplit(const float* __restrict__ W, ushort_t* __restrict__ hiT,
                       ushort_t* __restrict__ loT, int K, int M){
  int i = blockIdx.x*256 + threadIdx.x;
  if (i >= K*M) return;
  int k = i / M, m = i % M;
  ushort_t h, l;
  split2(W[i], h, l);
  hiT[(size_t)m*K + k] = h;
  loT[(size_t)m*K + k] = l;
}

// ---------------- bf16x3 split MFMA GEMM ----------------
// C[n,M] = (Ahi+Alo)[n,K] @ (Bhi+Blo)^T  with B stored transposed [M][K].
// ACT: 0 none->Cf ; 1 bias+leaky ; 2 bias. SPLIT_OUT: write Chi/Clo instead of Cf.
template<int BM, int BN, int WM, int WN, int ACT, int SPLIT_OUT>
__global__ __launch_bounds__(256) void gemm_mfma(
    const ushort_t* __restrict__ Ahi_g, const ushort_t* __restrict__ Alo_g,
    const ushort_t* __restrict__ Bhi_g, const ushort_t* __restrict__ Blo_g,
    const float* __restrict__ bias,
    float* __restrict__ Cf, ushort_t* __restrict__ Chi, ushort_t* __restrict__ Clo,
    int nrows, int K, int M){
  constexpr int FI = WM/16, FJ = WN/16;
  constexpr int WCOLS = BN/WN;
  __shared__ ushort_t sAhi[BM*32];
  __shared__ ushort_t sAlo[BM*32];
  __shared__ ushort_t sBhi[BN*32];
  __shared__ ushort_t sBlo[BN*32];
  const int tid  = threadIdx.x;
  const int wave = tid >> 6;
  const int lane = tid & 63;
  const int r0 = blockIdx.x * BM;
  const int c0 = blockIdx.y * BN;
  const int wr0 = (wave / WCOLS) * WM;
  const int wc0 = (wave % WCOLS) * WN;
  const int m = lane & 15, q = lane >> 4;

  v4f acc[FI][FJ];
#pragma unroll
  for (int i = 0; i < FI; ++i)
#pragma unroll
    for (int j = 0; j < FJ; ++j) acc[i][j] = (v4f){0.f,0.f,0.f,0.f};

  const int srow = lane >> 2;                        // row within 16-row chunk
  const int kqlog = (lane & 3) ^ ((srow >> 1) & 3);  // swizzled logical 16B chunk
  const int fsw = (q ^ ((m >> 1) & 3)) * 8;          // frag read: swizzled k elem offset

  for (int kt = 0; kt < K; kt += 32){
#pragma unroll
    for (int c = 0; c < BM/64; ++c){                 // each wave stages BM/64 16-row A-chunks
      int cc = c*4 + wave;
      int gr = r0 + cc*16 + srow;
      gr = min(gr, nrows - 1);
      size_t go = (size_t)gr*K + kt + kqlog*8;
      gload16(Ahi_g + go, &sAhi[cc*512]);
      gload16(Alo_g + go, &sAlo[cc*512]);
    }
    for (int cc = wave; cc < BN/16; cc += 4){
      int gr = c0 + cc*16 + srow;
      size_t go = (size_t)gr*K + kt + kqlog*8;
      gload16(Bhi_g + go, &sBhi[cc*512]);
      gload16(Blo_g + go, &sBlo[cc*512]);
    }
    __syncthreads();   // drains vmcnt (global_load_lds) per barrier semantics

    v8s ah[FI], al[FI], bh[FJ], bl[FJ];
#pragma unroll
    for (int i = 0; i < FI; ++i){
      int off = (wr0 + i*16 + m)*32 + fsw;
      ah[i] = *(const v8s*)&sAhi[off];
      al[i] = *(const v8s*)&sAlo[off];
    }
#pragma unroll
    for (int j = 0; j < FJ; ++j){
      int off = (wc0 + j*16 + m)*32 + fsw;
      bh[j] = *(const v8s*)&sBhi[off];
      bl[j] = *(const v8s*)&sBlo[off];
    }
#pragma unroll
    for (int i = 0; i < FI; ++i)
#pragma unroll
      for (int j = 0; j < FJ; ++j){
        acc[i][j] = __builtin_amdgcn_mfma_f32_16x16x32_bf16(ah[i], bh[j], acc[i][j], 0, 0, 0);
        acc[i][j] = __builtin_amdgcn_mfma_f32_16x16x32_bf16(ah[i], bl[j], acc[i][j], 0, 0, 0);
        acc[i][j] = __builtin_amdgcn_mfma_f32_16x16x32_bf16(al[i], bh[j], acc[i][j], 0, 0, 0);
      }
    __syncthreads();
  }

  // epilogue: C/D layout col = lane&15, row = (lane>>4)*4 + reg  [m89/m91]
#pragma unroll
  for (int i = 0; i < FI; ++i){
#pragma unroll
    for (int j = 0; j < FJ; ++j){
      int col = c0 + wc0 + j*16 + m;
      float bv = (ACT >= 1) ? bias[col] : 0.f;
#pragma unroll
      for (int r = 0; r < 4; ++r){
        int row = r0 + wr0 + i*16 + q*4 + r;
        if (row >= nrows) continue;
        float v = acc[i][j][r] + bv;
        if (ACT == 1) v = lk(v);
        size_t o = (size_t)row*M + col;
        if (SPLIT_OUT){
          ushort_t h, l; split2(v, h, l);
          Chi[o] = h; Clo[o] = l;
        } else {
          Cf[o] = v;
        }
      }
    }
  }
}

// ---------------- launch ----------------
extern "C" void kernel_launch(void* const* d_in, const int* in_sizes, int n_in,
                              void* d_out, int out_size, void* d_ws, size_t ws_size,
                              hipStream_t stream){
  const float* x   = (const float*)d_in[0];
  const int*   ei  = (const int*)  d_in[1];
  const float* ew  = (const float*)d_in[2];
  const float* W1  = (const float*)d_in[3];
  const float* b1  = (const float*)d_in[4];
  const float* g1  = (const float*)d_in[5];
  const float* be1 = (const float*)d_in[6];
  const float* W2  = (const float*)d_in[7];
  const float* b2  = (const float*)d_in[8];
  const float* g2  = (const float*)d_in[9];
  const float* be2 = (const float*)d_in[10];
  const float* W3  = (const float*)d_in[11];
  const float* b3  = (const float*)d_in[12];
  const float* g3  = (const float*)d_in[13];
  const float* be3 = (const float*)d_in[14];
  const float* Wl1 = (const float*)d_in[15];
  const float* bl1 = (const float*)d_in[16];
  const float* Wl2 = (const float*)d_in[17];
  const float* bl2 = (const float*)d_in[18];
  const int* src = ei;
  const int* dst = ei + NE;

  // ---- workspace: 2-slot rotation, total ~220 MB (proven budget) ----
  char* p = (char*)d_ws;
  auto carve = [&](size_t bytes)->void*{
    void* r = (void*)p;
    p += (bytes + 255) & ~(size_t)255;
    return r;
  };
  float*    dinv    = (float*)   carve((size_t)NN*4);
  int*      rp      = (int*)     carve((size_t)(NN+1)*4);
  int*      fill    = (int*)     carve((size_t)NN*4);    // counts, then cursor
  int*      bsum    = (int*)     carve(256*4);
  float*    stats   = (float*)   carve(1024*4);
  u64*      acc64   = (u64*)     carve((size_t)NN*8);
  int2*     csr_sw  = (int2*)    carve((size_t)NE*8);
  float*    S1      = (float*)   carve((size_t)NN*256*4);   // 102.4 MB slot
  float*    S2      = (float*)   carve((size_t)NN*256*4);   // 102.4 MB slot
  ushort_t* W1tH    = (ushort_t*)carve(128*256*2);
  ushort_t* W1tL    = (ushort_t*)carve(128*256*2);
  ushort_t* W2tH    = (ushort_t*)carve(256*256*2);
  ushort_t* W2tL    = (ushort_t*)carve(256*256*2);
  ushort_t* W3tH    = (ushort_t*)carve(256*256*2);
  ushort_t* W3tL    = (ushort_t*)carve(256*256*2);
  ushort_t* Wl1tH   = (ushort_t*)carve(256*256*2);
  ushort_t* Wl1tL   = (ushort_t*)carve(256*256*2);
  ushort_t* Wl2tH   = (ushort_t*)carve(256*32*2);
  ushort_t* Wl2tL   = (ushort_t*)carve(256*32*2);

  // split views of the two slots (hi array then lo array within one slot)
  ushort_t* S1h256 = (ushort_t*)S1;  ushort_t* S1l256 = S1h256 + (size_t)NN*256;
  ushort_t* S2h256 = (ushort_t*)S2;  ushort_t* S2l256 = S2h256 + (size_t)NN*256;
  ushort_t* S1h128 = (ushort_t*)S1;  ushort_t* S1l128 = S1h128 + (size_t)NN*128;  // ax split (K=128)

  const int nb = (NN + 1023) / 1024;
  const int spmm_blocks = (NN + 3) / 4;

  // graph preprocessing (shared by all 3 conv layers)
  zero_acc<<<(NN+255)/256, 256, 0, stream>>>(acc64, NN);
  edge_hist<<<(NE+255)/256, 256, 0, stream>>>(dst, ew, acc64, NE);
  finalize_acc<<<(NN+255)/256, 256, 0, stream>>>(acc64, dinv, fill, NN);
  scan_block<<<nb, 1024, 0, stream>>>(fill, rp, bsum, NN);
  scan_small<<<1, 128, 0, stream>>>(bsum, nb);
  scan_add<<<nb, 1024, 0, stream>>>(rp, fill, bsum, NN, NE);
  fill_csr_k<<<(NE+255)/256, 256, 0, stream>>>(src, dst, ew, dinv, fill, csr_sw, NE);

  // weight splits
  wsplit<<<(128*256+255)/256, 256, 0, stream>>>(W1,  W1tH,  W1tL,  128, 256);
  wsplit<<<(256*256+255)/256, 256, 0, stream>>>(W2,  W2tH,  W2tL,  256, 256);
  wsplit<<<(256*256+255)/256, 256, 0, stream>>>(W3,  W3tH,  W3tL,  256, 256);
  wsplit<<<(256*256+255)/256, 256, 0, stream>>>(Wl1, Wl1tH, Wl1tL, 256, 256);
  wsplit<<<(256*32 +255)/256, 256, 0, stream>>>(Wl2, Wl2tH, Wl2tL, 256, 32);

  dim3 gridBig((NN+127)/128, 2);
  dim3 gridOut((NN+127)/128, 1);

  auto run_bn = [&](const float* fin, ushort_t* hi, ushort_t* lo,
                    const float* g, const float* be){
    zero_stats<<<1, 512, 0, stream>>>(stats);
    bn_partial<<<(NN+255)/256, 256, 0, stream>>>(fin, stats, NN);
    bn_final<<<1, 256, 0, stream>>>(stats, g, be, NN);
    bn_apply_split<<<(int)(((size_t)NN*64 + 255)/256), 256, 0, stream>>>(fin, stats, hi, lo, NN);
  };

  // conv1 (aggregate-first: (A~ x) W1 + b1 == A~ (x W1) + b1):
  //   spmm on x (128 ch, one pass) -> S2 ; split -> S1 ; gemm+b1 -> S2 fp32
  spmm_half<<<spmm_blocks, 256, 0, stream>>>(x, rp, csr_sw, dinv, nullptr, S2, NN, 128, 0);
  split_f4<<<(NN*32+255)/256, 256, 0, stream>>>(S2, S1h128, S1l128, NN*32);
  gemm_mfma<128,128,64,64,2,0><<<gridBig, 256, 0, stream>>>(
      S1h128, S1l128, W1tH, W1tL, b1, S2, nullptr, nullptr, NN, 128, 256);
  run_bn(S2, S1h256, S1l256, g1, be1);

  // conv2: gemm S1(split) -> S2 fp32 ; spmm 2 half passes S2 -> S1 ; bn S1 -> S2 split
  gemm_mfma<128,128,64,64,0,0><<<gridBig, 256, 0, stream>>>(
      S1h256, S1l256, W2tH, W2tL, nullptr, S2, nullptr, nullptr, NN, 256, 256);
  spmm_half<<<spmm_blocks, 256, 0, stream>>>(S2, rp, csr_sw, dinv, b2, S1, NN, 256, 0);
  spmm_half<<<spmm_blocks, 256, 0, stream>>>(S2, rp, csr_sw, dinv, b2, S1, NN, 256, 128);
  run_bn(S1, S2h256, S2l256, g2, be2);

  // conv3: gemm S2(split) -> S1 fp32 ; spmm S1 -> S2 ; bn S2 -> S1 split
  gemm_mfma<128,128,64,64,0,0><<<gridBig, 256, 0, stream>>>(
      S2h256, S2l256, W3tH, W3tL, nullptr, S1, nullptr, nullptr, NN, 256, 256);
  spmm_half<<<spmm_blocks, 256, 0, stream>>>(S1, rp, csr_sw, dinv, b3, S2, NN, 256, 0);
  spmm_half<<<spmm_blocks, 256, 0, stream>>>(S1, rp, csr_sw, dinv, b3, S2, NN, 256, 128);
  run_bn(S2, S1h256, S1l256, g3, be3);

  // head: leaky(h @ Wl1 + bl1) -> S2 split ; then @ Wl2 + bl2 -> d_out
  gemm_mfma<128,128,64,64,1,1><<<gridBig, 256, 0, stream>>>(
      S1h256, S1l256, Wl1tH, Wl1tL, bl1, nullptr, S2h256, S2l256, NN, 256, 256);
  gemm_mfma<128,32,32,32,2,0><<<gridOut, 256, 0, stream>>>(
      S2h256, S2l256, Wl2tH, Wl2tL, bl2, (float*)d_out, nullptr, nullptr, NN, 256, 32);
}